// Round 8
// baseline (28.911 us; speedup 1.0000x reference)
//
#include <hip/hip_runtime.h>
#include <hip/hip_bf16.h>

#define DIM 256
#define NAGENT 64
#define NBATCH 256

typedef __bf16 bf16_t;
typedef bf16_t bf16x4 __attribute__((ext_vector_type(4)));
typedef bf16_t bf16x8 __attribute__((ext_vector_type(8)));
typedef float f32x4 __attribute__((ext_vector_type(4)));

// Prep: block b computes row b of Wc = bf16(Wh @ Ws @ Wa) and bc[b].
// 512 threads (8 waves) -> 1 block/CU placement (256 blocks over 256 CUs),
// halving per-CU Ws/Wa ingest vs the 1024-thread version (2 blocks/CU).
// Thread (kc = t>>6: k-chunk of 32, jg = t&63: 4 output cols, f32x4).
__global__ __launch_bounds__(512) void prep_kernel(
    const float* __restrict__ Wh, const float* __restrict__ Ws,
    const float* __restrict__ Wa, const float* __restrict__ ba,
    const float* __restrict__ bs, const float* __restrict__ bh,
    bf16_t* __restrict__ Wc, float* __restrict__ bcw) {
  const int b = blockIdx.x;
  const int t = threadIdx.x;
  const int jg = t & 63;
  const int kc = t >> 6;

  __shared__ float whl[DIM];      // Wh row b
  __shared__ float t1l[DIM];      // Whs row b
  __shared__ f32x4 part[8][64];   // 8 KB partials

  if (t < 64) *(f32x4*)&whl[t * 4] = *(const f32x4*)&Wh[b * DIM + t * 4];
  __syncthreads();

  // stage 1: t1 = whl @ Ws   (32 independent f32x4 loads per thread)
  {
    f32x4 a = {0.f, 0.f, 0.f, 0.f};
#pragma unroll
    for (int ki = 0; ki < 32; ++ki) {
      const int k = kc * 32 + ki;
      a += whl[k] * *(const f32x4*)&Ws[k * DIM + jg * 4];
    }
    part[kc][jg] = a;
  }
  __syncthreads();
  if (t < 64) {
    f32x4 s = part[0][t];
#pragma unroll
    for (int r = 1; r < 8; ++r) s += part[r][t];
    *(f32x4*)&t1l[t * 4] = s;
  }
  __syncthreads();

  // stage 2: Wc row = t1 @ Wa
  {
    f32x4 a = {0.f, 0.f, 0.f, 0.f};
#pragma unroll
    for (int ki = 0; ki < 32; ++ki) {
      const int k = kc * 32 + ki;
      a += t1l[k] * *(const f32x4*)&Wa[k * DIM + jg * 4];
    }
    part[kc][jg] = a;
  }
  __syncthreads();
  if (t < 64) {
    f32x4 s = part[0][t];
#pragma unroll
    for (int r = 1; r < 8; ++r) s += part[r][t];
    bf16x4 wb;
    wb[0] = (bf16_t)s[0]; wb[1] = (bf16_t)s[1];
    wb[2] = (bf16_t)s[2]; wb[3] = (bf16_t)s[3];
    *(bf16x4*)&Wc[b * DIM + t * 4] = wb;
    // bc[b] = dot(t1,ba) + dot(Wh[b],bs) + bh[b]
    const f32x4 t14 = *(const f32x4*)&t1l[t * 4];
    const f32x4 ba4 = *(const f32x4*)&ba[t * 4];
    const f32x4 wh4 = *(const f32x4*)&whl[t * 4];
    const f32x4 bs4 = *(const f32x4*)&bs[t * 4];
    const f32x4 pp = t14 * ba4 + wh4 * bs4;
    float p = pp[0] + pp[1] + pp[2] + pp[3];
#pragma unroll
    for (int s2 = 32; s2 > 0; s2 >>= 1) p += __shfl_down(p, s2, 64);
    if (t == 0) bcw[b] = p + bh[b];
  }
}

// Fused main (verbatim from R7): split-column, 2 blocks/CU.
// Block (b, half): builds full g for batch b, computes output cols
// half*128 .. half*128+127. 256 threads = 4 waves.
__global__ __launch_bounds__(256) void fused_kernel(
    const float* __restrict__ h, const bf16_t* __restrict__ Wc,
    const float* __restrict__ bcw, float* __restrict__ out) {
  const int b = blockIdx.x;
  const int half = blockIdx.y;
  const int t = threadIdx.x;

  __shared__ __align__(16) bf16_t g[NAGENT * DIM];  // 32 KB, XOR-swizzled
  __shared__ f32x4 ps[4][64];                       // 4 KB

  const float* hb = h + (size_t)b * NAGENT * DIM;
  const int cg = t & 63;   // cols cg*4 .. +3
  const int rg = t >> 6;   // row quartet: rows rg*16 .. +15

  f32x4 v[16];
  f32x4 s4 = {0.f, 0.f, 0.f, 0.f};
#pragma unroll
  for (int i = 0; i < 16; ++i) {
    v[i] = *(const f32x4*)&hb[(rg * 16 + i) * DIM + cg * 4];
    s4 += v[i];
  }
  ps[rg][cg] = s4;
  __syncthreads();
  f32x4 hs = ps[0][cg];
#pragma unroll
  for (int r = 1; r < 4; ++r) hs += ps[r][cg];

  const float inv = 1.0f / 63.0f;
#pragma unroll
  for (int i = 0; i < 16; ++i) {
    const int row = rg * 16 + i;
    const f32x4 gv = (hs - v[i]) * inv;
    bf16x4 gb;
    gb[0] = (bf16_t)gv[0]; gb[1] = (bf16_t)gv[1];
    gb[2] = (bf16_t)gv[2]; gb[3] = (bf16_t)gv[3];
    *(bf16x4*)&g[row * DIM + ((cg * 4) ^ ((row & 7) << 3))] = gb;
  }
  __syncthreads();

  // GEMM: wave w -> cols half*128 + w*32 .. +31, rows 0..63
  const int w = rg, lane = t & 63;
  const int lrow = lane & 15, lgrp = lane >> 4;
  const int colbase = half * 128 + w * 32;

  f32x4 acc[4][2];
#pragma unroll
  for (int rt = 0; rt < 4; ++rt)
#pragma unroll
    for (int ct = 0; ct < 2; ++ct) acc[rt][ct] = (f32x4){0.f, 0.f, 0.f, 0.f};

#pragma unroll
  for (int kk = 0; kk < 8; ++kk) {
    const int k0 = kk * 32 + lgrp * 8;
    bf16x8 bfrag[2];
#pragma unroll
    for (int ct = 0; ct < 2; ++ct) {
      const int col = colbase + ct * 16 + lrow;
      bfrag[ct] = *(const bf16x8*)&Wc[col * DIM + k0];
    }
#pragma unroll
    for (int rt = 0; rt < 4; ++rt) {
      const int arow = rt * 16 + lrow;
      const bf16x8 afrag =
          *(const bf16x8*)&g[arow * DIM + (k0 ^ ((arow & 7) << 3))];
      acc[rt][0] = __builtin_amdgcn_mfma_f32_16x16x32_bf16(afrag, bfrag[0], acc[rt][0], 0, 0, 0);
      acc[rt][1] = __builtin_amdgcn_mfma_f32_16x16x32_bf16(afrag, bfrag[1], acc[rt][1], 0, 0, 0);
    }
  }

  // epilogue: C/D layout col=lane&15, row=(lane>>4)*4+reg
  float* ob = out + (size_t)b * NAGENT * DIM;
#pragma unroll
  for (int ct = 0; ct < 2; ++ct) {
    const int col = colbase + ct * 16 + lrow;
    const float bcv = bcw[col];
#pragma unroll
    for (int rt = 0; rt < 4; ++rt) {
#pragma unroll
      for (int r = 0; r < 4; ++r) {
        const int row = rt * 16 + lgrp * 4 + r;
        const float val = acc[rt][ct][r] + bcv;
        ob[row * DIM + col] = val > 0.f ? val : 0.f;
      }
    }
  }
}

extern "C" void kernel_launch(void* const* d_in, const int* in_sizes, int n_in,
                              void* d_out, int out_size, void* d_ws, size_t ws_size,
                              hipStream_t stream) {
  const float* h  = (const float*)d_in[0];  // hidden_state (16384,256)
  const float* Wa = (const float*)d_in[1];  // W_act (256,256)
  const float* ba = (const float*)d_in[2];  // b_act (256,)
  const float* Ws = (const float*)d_in[3];  // W_sum (256,256)
  const float* bs = (const float*)d_in[4];  // b_sum (256,)
  const float* Wh = (const float*)d_in[5];  // W_head (256,256)
  const float* bh = (const float*)d_in[6];  // b_head (256,)
  float* out = (float*)d_out;

  char* ws = (char*)d_ws;
  bf16_t* Wc  = (bf16_t*)ws;                 // 128 KB
  float*  bcw = (float*)(ws + 128 * 1024);   // 1 KB

  prep_kernel<<<NBATCH, 512, 0, stream>>>(Wh, Ws, Wa, ba, bs, bh, Wc, bcw);
  fused_kernel<<<dim3(NBATCH, 2), 256, 0, stream>>>(h, Wc, bcw, out);
}

// Round 9
// 26.015 us; speedup vs baseline: 1.1113x; 1.1113x over previous
//
#include <hip/hip_runtime.h>
#include <hip/hip_bf16.h>

#define DIM 256
#define NAGENT 64
#define NBATCH 256

typedef __bf16 bf16_t;
typedef bf16_t bf16x4 __attribute__((ext_vector_type(4)));
typedef bf16_t bf16x8 __attribute__((ext_vector_type(8)));
typedef float f32x4 __attribute__((ext_vector_type(4)));

// Prep: 64 blocks x 1024 threads; block nb computes rows nb*4..+3 of
// Wc = bf16(Wh @ Ws @ Wa) and bc rows.
// Each Ws/Wa f32x4 load is reused across 4 rows (4x arithmetic intensity);
// 16 independent loads per thread per stage; 16 waves/CU hide L2 latency.
__global__ __launch_bounds__(1024) void prep_kernel(
    const float* __restrict__ Wh, const float* __restrict__ Ws,
    const float* __restrict__ Wa, const float* __restrict__ ba,
    const float* __restrict__ bs, const float* __restrict__ bh,
    bf16_t* __restrict__ Wc, float* __restrict__ bcw) {
  const int i0 = blockIdx.x * 4;
  const int t = threadIdx.x;
  const int jg = t & 63;     // output cols jg*4..+3
  const int kc = t >> 6;     // k-chunk 0..15 (16 k's each)

  __shared__ float whl[4][DIM];       // 4 KB : 4 Wh rows
  __shared__ float t1l[4][DIM];       // 4 KB : 4 Whs rows
  __shared__ f32x4 part[16][4][64];   // 64 KB: partials [kc][row][jg]

  ((float*)whl)[t] = Wh[i0 * DIM + t];  // 4 contiguous rows
  __syncthreads();

  // ---- stage 1: t1[r] = whl[r] @ Ws ----
  {
    f32x4 a0 = {0,0,0,0}, a1 = {0,0,0,0}, a2 = {0,0,0,0}, a3 = {0,0,0,0};
#pragma unroll
    for (int ki = 0; ki < 16; ++ki) {
      const int k = kc * 16 + ki;
      const f32x4 w4 = *(const f32x4*)&Ws[k * DIM + jg * 4];
      a0 += whl[0][k] * w4;
      a1 += whl[1][k] * w4;
      a2 += whl[2][k] * w4;
      a3 += whl[3][k] * w4;
    }
    part[kc][0][jg] = a0; part[kc][1][jg] = a1;
    part[kc][2][jg] = a2; part[kc][3][jg] = a3;
  }
  __syncthreads();
  if (t < 256) {
    const int r = t >> 6, c = t & 63;
    f32x4 s = part[0][r][c];
#pragma unroll
    for (int q = 1; q < 16; ++q) s += part[q][r][c];
    *(f32x4*)&t1l[r][c * 4] = s;
  }
  __syncthreads();

  // ---- stage 2: Wc[r] = t1[r] @ Wa ----
  {
    f32x4 a0 = {0,0,0,0}, a1 = {0,0,0,0}, a2 = {0,0,0,0}, a3 = {0,0,0,0};
#pragma unroll
    for (int ki = 0; ki < 16; ++ki) {
      const int k = kc * 16 + ki;
      const f32x4 w4 = *(const f32x4*)&Wa[k * DIM + jg * 4];
      a0 += t1l[0][k] * w4;
      a1 += t1l[1][k] * w4;
      a2 += t1l[2][k] * w4;
      a3 += t1l[3][k] * w4;
    }
    part[kc][0][jg] = a0; part[kc][1][jg] = a1;
    part[kc][2][jg] = a2; part[kc][3][jg] = a3;
  }
  __syncthreads();
  if (t < 256) {
    const int r = t >> 6, c = t & 63;  // wave r handles row r (t<256 = waves 0..3)
    f32x4 s = part[0][r][c];
#pragma unroll
    for (int q = 1; q < 16; ++q) s += part[q][r][c];
    bf16x4 wb;
    wb[0] = (bf16_t)s[0]; wb[1] = (bf16_t)s[1];
    wb[2] = (bf16_t)s[2]; wb[3] = (bf16_t)s[3];
    *(bf16x4*)&Wc[(i0 + r) * DIM + c * 4] = wb;
    // bias: bc[i0+r] = dot(t1[r],ba) + dot(whl[r],bs) + bh  (wave-local reduce)
    const f32x4 t14 = *(const f32x4*)&t1l[r][c * 4];
    const f32x4 ba4 = *(const f32x4*)&ba[c * 4];
    const f32x4 wh4 = *(const f32x4*)&whl[r][c * 4];
    const f32x4 bs4 = *(const f32x4*)&bs[c * 4];
    const f32x4 pp = t14 * ba4 + wh4 * bs4;
    float p = pp[0] + pp[1] + pp[2] + pp[3];
#pragma unroll
    for (int s2 = 32; s2 > 0; s2 >>= 1) p += __shfl_down(p, s2, 64);
    if (c == 0) bcw[i0 + r] = p + bh[i0 + r];
  }
}

// Fused main (verbatim from R7, proven 23.52): split-column, block (b, half)
// builds full g for batch b, computes output cols half*128..+127.
__global__ __launch_bounds__(256) void fused_kernel(
    const float* __restrict__ h, const bf16_t* __restrict__ Wc,
    const float* __restrict__ bcw, float* __restrict__ out) {
  const int b = blockIdx.x;
  const int half = blockIdx.y;
  const int t = threadIdx.x;

  __shared__ __align__(16) bf16_t g[NAGENT * DIM];  // 32 KB, XOR-swizzled
  __shared__ f32x4 ps[4][64];                       // 4 KB

  const float* hb = h + (size_t)b * NAGENT * DIM;
  const int cg = t & 63;   // cols cg*4 .. +3
  const int rg = t >> 6;   // rows rg*16 .. +15

  f32x4 v[16];
  f32x4 s4 = {0.f, 0.f, 0.f, 0.f};
#pragma unroll
  for (int i = 0; i < 16; ++i) {
    v[i] = *(const f32x4*)&hb[(rg * 16 + i) * DIM + cg * 4];
    s4 += v[i];
  }
  ps[rg][cg] = s4;
  __syncthreads();
  f32x4 hs = ps[0][cg];
#pragma unroll
  for (int r = 1; r < 4; ++r) hs += ps[r][cg];

  const float inv = 1.0f / 63.0f;
#pragma unroll
  for (int i = 0; i < 16; ++i) {
    const int row = rg * 16 + i;
    const f32x4 gv = (hs - v[i]) * inv;
    bf16x4 gb;
    gb[0] = (bf16_t)gv[0]; gb[1] = (bf16_t)gv[1];
    gb[2] = (bf16_t)gv[2]; gb[3] = (bf16_t)gv[3];
    *(bf16x4*)&g[row * DIM + ((cg * 4) ^ ((row & 7) << 3))] = gb;
  }
  __syncthreads();

  const int w = rg, lane = t & 63;
  const int lrow = lane & 15, lgrp = lane >> 4;
  const int colbase = half * 128 + w * 32;

  f32x4 acc[4][2];
#pragma unroll
  for (int rt = 0; rt < 4; ++rt)
#pragma unroll
    for (int ct = 0; ct < 2; ++ct) acc[rt][ct] = (f32x4){0.f, 0.f, 0.f, 0.f};

#pragma unroll
  for (int kk = 0; kk < 8; ++kk) {
    const int k0 = kk * 32 + lgrp * 8;
    bf16x8 bfrag[2];
#pragma unroll
    for (int ct = 0; ct < 2; ++ct) {
      const int col = colbase + ct * 16 + lrow;
      bfrag[ct] = *(const bf16x8*)&Wc[col * DIM + k0];
    }
#pragma unroll
    for (int rt = 0; rt < 4; ++rt) {
      const int arow = rt * 16 + lrow;
      const bf16x8 afrag =
          *(const bf16x8*)&g[arow * DIM + (k0 ^ ((arow & 7) << 3))];
      acc[rt][0] = __builtin_amdgcn_mfma_f32_16x16x32_bf16(afrag, bfrag[0], acc[rt][0], 0, 0, 0);
      acc[rt][1] = __builtin_amdgcn_mfma_f32_16x16x32_bf16(afrag, bfrag[1], acc[rt][1], 0, 0, 0);
    }
  }

  float* ob = out + (size_t)b * NAGENT * DIM;
#pragma unroll
  for (int ct = 0; ct < 2; ++ct) {
    const int col = colbase + ct * 16 + lrow;
    const float bcv = bcw[col];
#pragma unroll
    for (int rt = 0; rt < 4; ++rt) {
#pragma unroll
      for (int r = 0; r < 4; ++r) {
        const int row = rt * 16 + lgrp * 4 + r;
        const float val = acc[rt][ct][r] + bcv;
        ob[row * DIM + col] = val > 0.f ? val : 0.f;
      }
    }
  }
}

extern "C" void kernel_launch(void* const* d_in, const int* in_sizes, int n_in,
                              void* d_out, int out_size, void* d_ws, size_t ws_size,
                              hipStream_t stream) {
  const float* h  = (const float*)d_in[0];  // hidden_state (16384,256)
  const float* Wa = (const float*)d_in[1];  // W_act (256,256)
  const float* ba = (const float*)d_in[2];  // b_act (256,)
  const float* Ws = (const float*)d_in[3];  // W_sum (256,256)
  const float* bs = (const float*)d_in[4];  // b_sum (256,)
  const float* Wh = (const float*)d_in[5];  // W_head (256,256)
  const float* bh = (const float*)d_in[6];  // b_head (256,)
  float* out = (float*)d_out;

  char* ws = (char*)d_ws;
  bf16_t* Wc  = (bf16_t*)ws;                 // 128 KB
  float*  bcw = (float*)(ws + 128 * 1024);   // 1 KB

  prep_kernel<<<64, 1024, 0, stream>>>(Wh, Ws, Wa, ba, bs, bh, Wc, bcw);
  fused_kernel<<<dim3(NBATCH, 2), 256, 0, stream>>>(h, Wc, bcw, out);
}